// Round 1
// baseline (705.929 us; speedup 1.0000x reference)
//
#include <hip/hip_runtime.h>

#define NROWS 65536
#define ADIM  1024
#define CCLS  1000
#define SAUG  2
#define MROWS (NROWS + SAUG*CCLS)   /* 67536 */
#define MPAD  67584                 /* 264*256 */
#define NPAD  1024
#define NPART 4                     /* 4 col-splits; wave-col partials merged in LDS */
#define NEG_INF (-3.0e38f)

typedef __bf16 bf16x8 __attribute__((ext_vector_type(8)));
typedef float  f32x4  __attribute__((ext_vector_type(4)));
typedef unsigned short u16;

__device__ __forceinline__ unsigned pk2bf(float a, float b){
  unsigned ua = __float_as_uint(a), ub = __float_as_uint(b);
  ua = (ua + 0x7FFFu + ((ua>>16)&1u)) >> 16;
  ub = (ub + 0x7FFFu + ((ub>>16)&1u)) >> 16;
  return ua | (ub<<16);
}
__device__ __forceinline__ float bflo(unsigned u){ return __uint_as_float((u & 0xFFFFu) << 16); }
__device__ __forceinline__ float bfhi(unsigned u){ return __uint_as_float(u & 0xFFFF0000u); }

// ---------------- histogram of labels ----------------
__global__ void k_hist(const int* __restrict__ tgt, int* __restrict__ cnt){
  int i = blockIdx.x*blockDim.x + threadIdx.x;
  int stride = gridDim.x*blockDim.x;
  for (; i < NROWS; i += stride) atomicAdd(&cnt[tgt[i]], 1);
}

// ---------------- exclusive scan over 1000 counts ----------------
__global__ void k_scan(const int* __restrict__ cnt, int* __restrict__ start){
  __shared__ int s[1024];
  int t = threadIdx.x;
  int v = (t < CCLS) ? cnt[t] : 0;
  s[t] = v;
  __syncthreads();
  for (int off = 1; off < 1024; off <<= 1){
    int u = (t >= off) ? s[t-off] : 0;
    __syncthreads();
    s[t] += u;
    __syncthreads();
  }
  if (t < CCLS) start[t] = s[t] - v;   // exclusive
}

// ---------------- scatter row indices grouped by class ----------------
__global__ void k_scatter(const int* __restrict__ tgt, const int* __restrict__ start,
                          int* __restrict__ pos, int* __restrict__ sorted){
  int i = blockIdx.x*blockDim.x + threadIdx.x;
  int stride = gridDim.x*blockDim.x;
  for (; i < NROWS; i += stride){
    int c = tgt[i];
    int r = atomicAdd(&pos[c], 1);
    sorted[start[c] + r] = i;
  }
}

// ---------------- x rows -> bf16 ----------------
__global__ void k_cvt_x(const float* __restrict__ x, u16* __restrict__ xb){
  size_t i = ((size_t)blockIdx.x*blockDim.x + threadIdx.x)*8;
  float4 a = *(const float4*)(x+i);
  float4 b = *(const float4*)(x+i+4);
  uint4 o;
  o.x = pk2bf(a.x,a.y); o.y = pk2bf(a.z,a.w);
  o.z = pk2bf(b.x,b.y); o.w = pk2bf(b.z,b.w);
  *(uint4*)(xb+i) = o;
}

// ---------------- zero pad tail rows of xb ----------------
__global__ void k_pad(u16* __restrict__ xb){
  size_t i = ((size_t)blockIdx.x*blockDim.x + threadIdx.x)*8 + (size_t)MROWS*ADIM;
  uint4 z = {0u,0u,0u,0u};
  *(uint4*)(xb+i) = z;
}

// ---------------- fc_w -> bf16 (pad classes to 1024 with zeros) ----------------
__global__ void k_cvt_w(const float* __restrict__ w, u16* __restrict__ wb){
  size_t i = ((size_t)blockIdx.x*blockDim.x + threadIdx.x)*8;
  int row = (int)(i >> 10);
  uint4 o = {0u,0u,0u,0u};
  if (row < CCLS){
    float4 a = *(const float4*)(w+i);
    float4 b = *(const float4*)(w+i+4);
    o.x = pk2bf(a.x,a.y); o.y = pk2bf(a.z,a.w);
    o.z = pk2bf(b.x,b.y); o.w = pk2bf(b.z,b.w);
  }
  *(uint4*)(wb+i) = o;
}

// ---------------- combined bias (NEG_INF masks pad classes) ----------------
__global__ void k_bias(const float* __restrict__ fc_b, const float* __restrict__ ba,
                       float* __restrict__ biasv){
  int c = blockIdx.x*blockDim.x + threadIdx.x;
  if (c < NPAD) biasv[c] = (c < CCLS) ? fc_b[c] - ba[c] : NEG_INF;
}

// ---------------- per-class stats + augmentation rows (reads/writes bf16 xb) ----
__global__ void k_stats(const u16* __restrict__ xb_in, const int* __restrict__ sorted,
                        const int* __restrict__ cnt, const int* __restrict__ start,
                        const float* __restrict__ amt_p, const float* __restrict__ cov_p,
                        const float* __restrict__ ave_p, const float* __restrict__ eps,
                        u16* __restrict__ xb){
  int c = blockIdx.x;
  int t = threadIdx.x;
  int col = t*4;
  int n = cnt[c];
  int st = start[c];
  float s[4] = {0.f,0.f,0.f,0.f}, q[4] = {0.f,0.f,0.f,0.f};
  for (int i = 0; i < n; i++){
    int row = sorted[st + i];
    const uint2 uv = *(const uint2*)(xb_in + (size_t)row*ADIM + col);
    float v0 = bflo(uv.x), v1 = bfhi(uv.x), v2 = bflo(uv.y), v3 = bfhi(uv.y);
    s[0]+=v0; s[1]+=v1; s[2]+=v2; s[3]+=v3;
    q[0]+=v0*v0; q[1]+=v1*v1; q[2]+=v2*v2; q[3]+=v3*v3;
  }
  float cf = (float)n;
  float cc = (n == 0) ? 1.f : cf;
  float wgt = cf / (cf + amt_p[c] + 1e-10f);
  float4 cv = *(const float4*)(cov_p + (size_t)c*ADIM + col);
  float4 av = *(const float4*)(ave_p + (size_t)c*ADIM + col);
  float cvp[4] = {cv.x,cv.y,cv.z,cv.w};
  float avp[4] = {av.x,av.y,av.z,av.w};
  float ncov[4], nave[4];
  #pragma unroll
  for (int j = 0; j < 4; j++){
    float ave = s[j]/cc;
    float var = (q[j] - 2.f*ave*s[j] + cf*ave*ave)/cc;
    if (var <= 0.f) var = 1e-10f;
    float add = wgt*(1.f-wgt)*(avp[j]-ave)*(avp[j]-ave);
    ncov[j] = cvp[j]*(1.f-wgt) + var*wgt + add;
    nave[j] = avp[j]*(1.f-wgt) + ave*wgt;
  }
  #pragma unroll
  for (int s_ = 0; s_ < SAUG; s_++){
    size_t eoff = ((size_t)(s_*CCLS + c))*ADIM + col;
    size_t roff = ((size_t)(NROWS + s_*CCLS + c))*ADIM + col;
    const float4 e = *(const float4*)(eps + eoff);
    uint2 o;
    o.x = pk2bf(nave[0]+ncov[0]*e.x, nave[1]+ncov[1]*e.y);
    o.y = pk2bf(nave[2]+ncov[2]*e.z, nave[3]+ncov[3]*e.w);
    *(uint2*)(xb + roff) = o;
  }
}

// ---------------- MFMA GEMM + softmax partials (8-phase-family schedule) -------
// tile 256 rows x 256 cols, BK=32, 8 waves (2M x 4N), wave tile 128x64
// 4-deep LDS ring (4 x 32KB), prefetch distance 3, counted vmcnt(10)
// LDS swizzle: off ^= ((off>>7)&3)<<4  (involution; applied to gload source + ds_read)
__global__ __launch_bounds__(512,2) void k_gemm_part(
    const u16* __restrict__ xb, const u16* __restrict__ wb,
    const float* __restrict__ biasv, const int* __restrict__ tgt,
    float* __restrict__ pm, float* __restrict__ pl, float* __restrict__ plab){
  extern __shared__ char smem[];
  const int t = threadIdx.x;
  const int lane = t & 63;
  const int wv = t >> 6;       // 0..7
  const int wr = wv >> 2;      // M half (128 rows)
  const int wc = wv & 3;       // N quarter (64 cols)
  const int col = lane & 15;
  const int quad = lane >> 4;

  // bijective XCD-chunk swizzle: 1056 blocks, 8 XCDs, 132 per chunk
  const int bid = blockIdx.x;
  const int wg  = (bid & 7)*132 + (bid >> 3);
  const int sp  = wg & 3;                  // col split (256 cols each)
  const int row0 = (wg >> 2) * 256;        // 264 row tiles

  const unsigned lds0 = (unsigned)(size_t)((__attribute__((address_space(3))) char*)smem);

  // swizzled ds_read addresses (within one 32KB buffer)
  unsigned aoff[8], boff[4];
  #pragma unroll
  for (int m = 0; m < 8; m++){
    unsigned lin = (unsigned)((wr*128 + m*16 + col)*64 + quad*16);
    aoff[m] = lds0 + (lin ^ (((lin >> 7) & 3u) << 4));
  }
  #pragma unroll
  for (int n = 0; n < 4; n++){
    unsigned lin = (unsigned)((wc*64 + n*16 + col)*64 + quad*16);
    boff[n] = lds0 + 16384u + (lin ^ (((lin >> 7) & 3u) << 4));
  }

  // staging: per thread 4 global_load_lds x16B per K-tile (A:2, B:2)
  // linear LDS dest, inverse-swizzled global source (rule 21)
  const u16* src[4];
  int dstoff[4];
  {
    const u16* gA = xb + (size_t)row0*ADIM;
    const u16* gB = wb + (size_t)(sp*256)*ADIM;
    #pragma unroll
    for (int j = 0; j < 4; j++){
      unsigned d = (unsigned)((j & 1)*8192 + wv*1024 + lane*16);
      unsigned s = d ^ ((((unsigned)lane >> 3) & 3u) << 4);
      src[j] = (j < 2 ? gA : gB) + (size_t)(s >> 6)*ADIM + ((s & 63u) >> 1);
      dstoff[j] = (j < 2 ? 0 : 16384) + (j & 1)*8192 + wv*1024;
    }
  }

#define STG(tile, nb, j) \
  __builtin_amdgcn_global_load_lds( \
      (const __attribute__((address_space(1))) void*)(src[j] + (size_t)(tile)*32), \
      (__attribute__((address_space(3))) void*)(smem + (nb)*32768 + dstoff[j]), 16, 0, 0)

  f32x4 acc[8][4];
  const f32x4 z = {0.f,0.f,0.f,0.f};
  #pragma unroll
  for (int m = 0; m < 8; m++)
    #pragma unroll
    for (int n = 0; n < 4; n++) acc[m][n] = z;

  // prologue: stage K-tiles 0,1,2 into ring bufs 0,1,2
  #pragma unroll
  for (int p = 0; p < 3; p++){
    STG(p, p, 0); STG(p, p, 1); STG(p, p, 2); STG(p, p, 3);
  }

  // main loop: compute tile kt from buf kt&3, stage tile kt+3 into (kt+3)&3
  for (int kt = 0; kt < 29; kt++){
    const int cb = kt & 3, nb = (kt + 3) & 3;
    const unsigned cbo = (unsigned)(cb << 15);
    bf16x8 af[4], bfr[4];
    // ---- phase 1: issue 2 stage calls, arrive-sync, Mfrags 0-3 x Nfrags 0-3
    STG(kt+3, nb, 0); STG(kt+3, nb, 1);
    asm volatile("s_waitcnt vmcnt(10)" ::: "memory");   // tile kt fully landed (mine)
    __builtin_amdgcn_sched_barrier(0);
    __builtin_amdgcn_s_barrier();                       // everyone's slices landed
    __builtin_amdgcn_sched_barrier(0);
    #pragma unroll
    for (int m = 0; m < 4; m++)
      asm volatile("ds_read_b128 %0, %1" : "=v"(af[m]) : "v"(aoff[m]+cbo));
    #pragma unroll
    for (int n = 0; n < 4; n++)
      asm volatile("ds_read_b128 %0, %1" : "=v"(bfr[n]) : "v"(boff[n]+cbo));
    asm volatile("s_waitcnt lgkmcnt(0)" ::: "memory");
    __builtin_amdgcn_sched_barrier(0);
    __builtin_amdgcn_s_setprio(1);
    #pragma unroll
    for (int m = 0; m < 4; m++)
      #pragma unroll
      for (int n = 0; n < 4; n++)
        acc[m][n] = __builtin_amdgcn_mfma_f32_16x16x32_bf16(af[m], bfr[n], acc[m][n], 0, 0, 0);
    __builtin_amdgcn_s_setprio(0);
    // ---- phase 2: issue 2 stage calls, Mfrags 4-7 x Nfrags 0-3
    STG(kt+3, nb, 2); STG(kt+3, nb, 3);
    #pragma unroll
    for (int m = 0; m < 4; m++)
      asm volatile("ds_read_b128 %0, %1" : "=v"(af[m]) : "v"(aoff[4+m]+cbo));
    asm volatile("s_waitcnt lgkmcnt(0)" ::: "memory");
    __builtin_amdgcn_sched_barrier(0);
    __builtin_amdgcn_s_setprio(1);
    #pragma unroll
    for (int m = 0; m < 4; m++)
      #pragma unroll
      for (int n = 0; n < 4; n++)
        acc[4+m][n] = __builtin_amdgcn_mfma_f32_16x16x32_bf16(af[m], bfr[n], acc[4+m][n], 0, 0, 0);
    __builtin_amdgcn_s_setprio(0);
    __builtin_amdgcn_sched_barrier(0);
    __builtin_amdgcn_s_barrier();                       // all reads of buf cb done
  }

  // tail: tiles 29,30,31 already staged; drain once, no more barriers needed
  asm volatile("s_waitcnt vmcnt(0)" ::: "memory");
  __builtin_amdgcn_sched_barrier(0);
  __builtin_amdgcn_s_barrier();
  #pragma unroll
  for (int kt = 29; kt < 32; kt++){
    const unsigned cbo = (unsigned)((kt & 3) << 15);
    bf16x8 af[4], bfr[4];
    #pragma unroll
    for (int m = 0; m < 4; m++)
      asm volatile("ds_read_b128 %0, %1" : "=v"(af[m]) : "v"(aoff[m]+cbo));
    #pragma unroll
    for (int n = 0; n < 4; n++)
      asm volatile("ds_read_b128 %0, %1" : "=v"(bfr[n]) : "v"(boff[n]+cbo));
    asm volatile("s_waitcnt lgkmcnt(0)" ::: "memory");
    __builtin_amdgcn_sched_barrier(0);
    #pragma unroll
    for (int m = 0; m < 4; m++)
      #pragma unroll
      for (int n = 0; n < 4; n++)
        acc[m][n] = __builtin_amdgcn_mfma_f32_16x16x32_bf16(af[m], bfr[n], acc[m][n], 0, 0, 0);
    #pragma unroll
    for (int m = 0; m < 4; m++)
      asm volatile("ds_read_b128 %0, %1" : "=v"(af[m]) : "v"(aoff[4+m]+cbo));
    asm volatile("s_waitcnt lgkmcnt(0)" ::: "memory");
    __builtin_amdgcn_sched_barrier(0);
    #pragma unroll
    for (int m = 0; m < 4; m++)
      #pragma unroll
      for (int n = 0; n < 4; n++)
        acc[4+m][n] = __builtin_amdgcn_mfma_f32_16x16x32_bf16(af[m], bfr[n], acc[4+m][n], 0, 0, 0);
  }
#undef STG

  // ---- epilogue: per-row max/expsum/label over wave's 64 cols, then LDS-merge
  float bias[4];
  #pragma unroll
  for (int n = 0; n < 4; n++) bias[n] = biasv[sp*256 + wc*64 + n*16 + col];

  __syncthreads();                    // all waves done with LDS tiles
  float* red = (float*)smem;          // [3][256][4] = 12 KB

  #pragma unroll
  for (int m = 0; m < 8; m++){
    #pragma unroll
    for (int rg = 0; rg < 4; rg++){
      const int rb = wr*128 + m*16 + quad*4 + rg;
      const int gr = row0 + rb;
      int lbl = -1;
      if (gr < NROWS) lbl = tgt[gr];
      else if (gr < MROWS){ int a_ = gr - NROWS; lbl = (a_ < CCLS) ? a_ : a_ - CCLS; }
      float lg[4];
      float mx = NEG_INF, lv = NEG_INF;
      #pragma unroll
      for (int n = 0; n < 4; n++){
        float v = acc[m][n][rg] + bias[n];
        lg[n] = v;
        mx = fmaxf(mx, v);
        int c = sp*256 + wc*64 + n*16 + col;
        lv = (c == lbl) ? v : lv;
      }
      #pragma unroll
      for (int o = 1; o < 16; o <<= 1) mx = fmaxf(mx, __shfl_xor(mx, o));
      float se = 0.f;
      #pragma unroll
      for (int n = 0; n < 4; n++) se += __expf(lg[n] - mx);
      #pragma unroll
      for (int o = 1; o < 16; o <<= 1) se += __shfl_xor(se, o);
      #pragma unroll
      for (int o = 1; o < 16; o <<= 1) lv = fmaxf(lv, __shfl_xor(lv, o));
      if (col == 0){
        red[0*1024 + rb*4 + wc] = mx;
        red[1*1024 + rb*4 + wc] = se;
        red[2*1024 + rb*4 + wc] = lv;
      }
    }
  }
  __syncthreads();
  if (t < 256){
    float m0 = red[t*4+0], m1 = red[t*4+1], m2 = red[t*4+2], m3 = red[t*4+3];
    float mx = fmaxf(fmaxf(m0,m1), fmaxf(m2,m3));
    float l  = red[1024+t*4+0]*__expf(m0-mx) + red[1024+t*4+1]*__expf(m1-mx)
             + red[1024+t*4+2]*__expf(m2-mx) + red[1024+t*4+3]*__expf(m3-mx);
    float lv = fmaxf(fmaxf(red[2048+t*4+0],red[2048+t*4+1]),
                     fmaxf(red[2048+t*4+2],red[2048+t*4+3]));
    size_t idx = (size_t)sp*MPAD + (size_t)(row0 + t);
    pm[idx]   = mx;
    pl[idx]   = l;
    plab[idx] = lv;
  }
}

// ---------------- merge 4 partials -> loss (scaled, atomic into out) ----------------
__global__ void k_merge(const float* __restrict__ pm, const float* __restrict__ pl,
                        const float* __restrict__ plab, float* __restrict__ out){
  int r = blockIdx.x*256 + threadIdx.x;
  float v = 0.f;
  if (r < MROWS){
    float m = NEG_INF, lb = NEG_INF;
    #pragma unroll
    for (int s = 0; s < NPART; s++){
      m  = fmaxf(m,  pm[(size_t)s*MPAD + r]);
      lb = fmaxf(lb, plab[(size_t)s*MPAD + r]);
    }
    float l = 0.f;
    #pragma unroll
    for (int s = 0; s < NPART; s++)
      l += pl[(size_t)s*MPAD + r]*__expf(pm[(size_t)s*MPAD + r] - m);
    v = (m + __logf(l) - lb) * (1.0f/(float)MROWS);
  }
  #pragma unroll
  for (int o = 32; o > 0; o >>= 1) v += __shfl_xor(v, o);
  if ((threadIdx.x & 63) == 0) atomicAdd(out, v);
}

extern "C" void kernel_launch(void* const* d_in, const int* in_sizes, int n_in,
                              void* d_out, int out_size, void* d_ws, size_t ws_size,
                              hipStream_t stream) {
  const float* x     = (const float*)d_in[0];
  const float* eps   = (const float*)d_in[1];
  const float* fc_w  = (const float*)d_in[2];
  const float* fc_b  = (const float*)d_in[3];
  const float* ba    = (const float*)d_in[4];
  const float* cov_p = (const float*)d_in[5];
  const float* ave_p = (const float*)d_in[6];
  const float* amt_p = (const float*)d_in[7];
  const int*   tgt   = (const int*)d_in[8];
  float* out = (float*)d_out;

  char* ws = (char*)d_ws;
  u16*   xb    = (u16*)(ws);                         // 138,412,032 B
  u16*   wb    = (u16*)(ws + 138412032u);            // 2,097,152 B
  float* biasv = (float*)(ws + 140509184u);          // 4096 B
  int*   sorted= (int*)(ws + 140513280u);            // 262,144 B
  int*   cnt   = (int*)(ws + 140775424u);            // 4096
  int*   pos   = (int*)(ws + 140779520u);            // 4096
  int*   start = (int*)(ws + 140783616u);            // 4096
  float* pm    = (float*)(ws + 140787712u);          // 2,162,688 (using 4*MPAD*4)
  float* pl    = (float*)(ws + 142950400u);          // 2,162,688
  float* plab  = (float*)(ws + 145113088u);          // 2,162,688

  static int cfg = 0;
  if (!cfg){
    hipFuncSetAttribute((const void*)k_gemm_part,
                        hipFuncAttributeMaxDynamicSharedMemorySize, 131072);
    cfg = 1;
  }

  hipMemsetAsync(cnt, 0, 12288, stream);             // cnt, pos, start
  hipMemsetAsync(out, 0, sizeof(float), stream);

  k_hist   <<<256, 256, 0, stream>>>(tgt, cnt);
  k_scan   <<<1, 1024, 0, stream>>>(cnt, start);
  k_scatter<<<256, 256, 0, stream>>>(tgt, start, pos, sorted);
  k_cvt_x  <<<32768, 256, 0, stream>>>(x, xb);
  k_pad    <<<24, 256, 0, stream>>>(xb);
  k_cvt_w  <<<512, 256, 0, stream>>>(fc_w, wb);
  k_bias   <<<4, 256, 0, stream>>>(fc_b, ba, biasv);
  k_stats  <<<CCLS, 256, 0, stream>>>(xb, sorted, cnt, start, amt_p, cov_p, ave_p, eps, xb);
  k_gemm_part<<<1056, 512, 131072, stream>>>(xb, wb, biasv, tgt, pm, pl, plab);
  k_merge  <<<264, 256, 0, stream>>>(pm, pl, plab, out);
}